// Round 1
// baseline (9.557 us; speedup 1.0000x reference)
//
#include <hip/hip_runtime.h>
#include <math.h>

// Problem dims (from reference): A=24, D=16.
// Output layout, concatenated flat in return order:
//   [0..23]    out          = tanh(dec stack)
//   [24..87]   in_diff_sum  = pairwise L2 over rows of x.reshape(8,3)
//   [88..151]  lat_diff_sum = all zeros (faithful bug reproduction)
//   [152..167] lat_repr     = y (latent, 16)

#define AE_A 24
#define AE_D 16

__global__ __launch_bounds__(64) void ae_fwd_kernel(
    const float* __restrict__ x,
    const float* __restrict__ ew0, const float* __restrict__ eb0,
    const float* __restrict__ ew1, const float* __restrict__ eb1,
    const float* __restrict__ ew2, const float* __restrict__ eb2,
    const float* __restrict__ ew3, const float* __restrict__ eb3,
    const float* __restrict__ dw0, const float* __restrict__ db0,
    const float* __restrict__ dw1, const float* __restrict__ db1,
    const float* __restrict__ dw2, const float* __restrict__ db2,
    const float* __restrict__ dw3, const float* __restrict__ db3,
    float* __restrict__ out)
{
    __shared__ float xs[AE_A];
    __shared__ float ha[AE_A];
    __shared__ float hb[AE_A];
    __shared__ float y[AE_D];

    const int t = threadIdx.x;

    if (t < AE_A) xs[t] = x[t];
    __syncthreads();

    // in_diff_sum (64 entries) + lat_diff_sum (64 zeros)
    {
        const int m = t >> 3;
        const int n = t & 7;
        const float d0 = xs[m * 3 + 0] - xs[n * 3 + 0];
        const float d1 = xs[m * 3 + 1] - xs[n * 3 + 1];
        const float d2 = xs[m * 3 + 2] - xs[n * 3 + 2];
        out[24 + t] = sqrtf(d0 * d0 + d1 * d1 + d2 * d2);
        out[88 + t] = 0.0f;
    }

    // enc0: ha = relu(ew0 @ xs + eb0)   [24x24]
    if (t < AE_A) {
        float acc = eb0[t];
        #pragma unroll
        for (int k = 0; k < AE_A; ++k) acc += ew0[t * AE_A + k] * xs[k];
        ha[t] = fmaxf(acc, 0.0f);
    }
    __syncthreads();

    // enc1: hb = relu(ew1 @ ha + eb1)   [24x24]
    if (t < AE_A) {
        float acc = eb1[t];
        #pragma unroll
        for (int k = 0; k < AE_A; ++k) acc += ew1[t * AE_A + k] * ha[k];
        hb[t] = fmaxf(acc, 0.0f);
    }
    __syncthreads();

    // enc2: ha = relu(ew2 @ hb + eb2)   [24x24]
    if (t < AE_A) {
        float acc = eb2[t];
        #pragma unroll
        for (int k = 0; k < AE_A; ++k) acc += ew2[t * AE_A + k] * hb[k];
        ha[t] = fmaxf(acc, 0.0f);
    }
    __syncthreads();

    // enc3: y = ew3 @ ha + eb3          [16x24]  -> latent, also lat_repr
    if (t < AE_D) {
        float acc = eb3[t];
        #pragma unroll
        for (int k = 0; k < AE_A; ++k) acc += ew3[t * AE_A + k] * ha[k];
        y[t] = acc;
        out[152 + t] = acc;
    }
    __syncthreads();

    // dec0: ha = relu(dw0 @ y + db0)    [24x16]
    if (t < AE_A) {
        float acc = db0[t];
        #pragma unroll
        for (int k = 0; k < AE_D; ++k) acc += dw0[t * AE_D + k] * y[k];
        ha[t] = fmaxf(acc, 0.0f);
    }
    __syncthreads();

    // dec1: hb = relu(dw1 @ ha + db1)   [24x24]
    if (t < AE_A) {
        float acc = db1[t];
        #pragma unroll
        for (int k = 0; k < AE_A; ++k) acc += dw1[t * AE_A + k] * ha[k];
        hb[t] = fmaxf(acc, 0.0f);
    }
    __syncthreads();

    // dec2: ha = relu(dw2 @ hb + db2)   [24x24]
    if (t < AE_A) {
        float acc = db2[t];
        #pragma unroll
        for (int k = 0; k < AE_A; ++k) acc += dw2[t * AE_A + k] * hb[k];
        ha[t] = fmaxf(acc, 0.0f);
    }
    __syncthreads();

    // dec3: out = tanh(dw3 @ ha + db3)  [24x24]
    if (t < AE_A) {
        float acc = db3[t];
        #pragma unroll
        for (int k = 0; k < AE_A; ++k) acc += dw3[t * AE_A + k] * ha[k];
        out[t] = tanhf(acc);
    }
}

extern "C" void kernel_launch(void* const* d_in, const int* in_sizes, int n_in,
                              void* d_out, int out_size, void* d_ws, size_t ws_size,
                              hipStream_t stream) {
    (void)in_sizes; (void)n_in; (void)d_ws; (void)ws_size; (void)out_size;

    const float* x   = (const float*)d_in[0];
    const float* ew0 = (const float*)d_in[1];
    const float* eb0 = (const float*)d_in[2];
    const float* ew1 = (const float*)d_in[3];
    const float* eb1 = (const float*)d_in[4];
    const float* ew2 = (const float*)d_in[5];
    const float* eb2 = (const float*)d_in[6];
    const float* ew3 = (const float*)d_in[7];
    const float* eb3 = (const float*)d_in[8];
    const float* dw0 = (const float*)d_in[9];
    const float* db0 = (const float*)d_in[10];
    const float* dw1 = (const float*)d_in[11];
    const float* db1 = (const float*)d_in[12];
    const float* dw2 = (const float*)d_in[13];
    const float* db2 = (const float*)d_in[14];
    const float* dw3 = (const float*)d_in[15];
    const float* db3 = (const float*)d_in[16];
    float* out = (float*)d_out;

    ae_fwd_kernel<<<1, 64, 0, stream>>>(
        x, ew0, eb0, ew1, eb1, ew2, eb2, ew3, eb3,
        dw0, db0, dw1, db1, dw2, db2, dw3, db3, out);
}